// Round 2
// baseline (256.039 us; speedup 1.0000x reference)
//
#include <hip/hip_runtime.h>

// Problem constants (B,C,H,W fixed by setup_inputs)
#define BB  16
#define HH  384
#define WW  1280
#define TPB 128   // threads per block; each thread owns VEC=2 columns
#define VEC 2     // columns per thread: dwordx2 center loads halve VMEM
                  // instruction count per column (R2 theory: stall-per-load-
                  // instruction bound, not bytes; R1 showed more waves ≠ faster)
#define ROWS 16   // rows per strip: 24 strips; grid 5x24x16 = 1920 blocks
                  // x 2 waves = 3840 waves = 15/CU (fits 4-waves/SIMD VGPR tier)
#define NSLOT 64  // accumulator slots, one 64B line each

// 4-value row fetch for a column pair [x0, x0+1] with zero padding:
// l = col x0-1, (a,b) = cols x0,x0+1 (one dwordx2), r = col x0+2.
__device__ __forceinline__ void load_row4(const float* __restrict__ plane, int i, int x0,
                                          float& l, float& a, float& b, float& r) {
    const float* row = plane + (size_t)i * WW;
    const float2 ab = *reinterpret_cast<const float2*>(row + x0);  // 8B-aligned
    a = ab.x; b = ab.y;
    l = (x0 > 0)        ? row[x0 - 1]   : 0.f;
    r = (x0 + VEC < WW) ? row[x0 + VEC] : 0.f;
}

// Per-column finish: cross products, normalize (rsq), |pred-gt| sum over xyz.
__device__ __forceinline__ float normal_absdiff(
    float gx0, float gx1, float gx2, float gx3, float gx4, float gx5,
    float gy0, float gy1, float gy2, float gy3, float gy4, float gy5)
{
    float n0p = gx1 * gy2 - gx2 * gy1;
    float n1p = gx2 * gy0 - gx0 * gy2;
    float n2p = gx0 * gy1 - gx1 * gy0;
    float n0g = gx4 * gy5 - gx5 * gy4;
    float n1g = gx5 * gy3 - gx3 * gy5;
    float n2g = gx3 * gy4 - gx4 * gy3;
    float sp = n0p * n0p + n1p * n1p + n2p * n2p;
    float sg = n0g * n0g + n1g * n1g + n2g * n2g;
    // ref: normal/(sqrt(s)+1e-10); rsq rel-err ~2e-6; guard s~0 -> 0
    float ip = (sp > 1e-20f) ? __builtin_amdgcn_rsqf(sp) : 0.f;
    float ig = (sg > 1e-20f) ? __builtin_amdgcn_rsqf(sg) : 0.f;
    return fabsf(n0p * ip - n0g * ig) + fabsf(n1p * ip - n1g * ig)
         + fabsf(n2p * ip - n2g * ig);
}

__global__ __launch_bounds__(TPB)   // no min-waves arg: R3 showed it forces spills
void NormalLoss_44478681317469_main(const float* __restrict__ pred,
                                    const float* __restrict__ gt,
                                    const float* __restrict__ mask,
                                    double* __restrict__ acc)
{
    const int jp = blockIdx.x * TPB + threadIdx.x;   // column-pair index [0,640)
    const int x0 = jp * VEC;                         // left column of the pair
    const int r0 = blockIdx.y * ROWS;                // strip start row
    const int b  = blockIdx.z;

    const float* pl[6];
#pragma unroll
    for (int c = 0; c < 3; ++c) {
        pl[c]     = pred + (size_t)(b * 3 + c) * HH * WW;
        pl[3 + c] = gt   + (size_t)(b * 3 + c) * HH * WW;
    }
    const float* mpl = mask + (size_t)b * HH * WW;

    // Rolling D (horiz diff) / T (horiz sum) state for rows i-1, i; per column
    // of the pair (suffix a = col x0, b = col x0+1).
    float Dm1a[6], Dm1b[6], D0a[6], D0b[6];
    float Tm1a[6], Tm1b[6], T0a[6], T0b[6];
    // Raw lookahead: row i+1 currently in flight from memory.
    float Rl[6], Ra[6], Rb[6], Rr[6];

#pragma unroll
    for (int c = 0; c < 6; ++c) {
        if (r0 > 0) {   // uniform per block
            float l, a, bb, r; load_row4(pl[c], r0 - 1, x0, l, a, bb, r);
            float s = a + bb;
            Dm1a[c] = bb - l; Dm1b[c] = r - a;
            Tm1a[c] = l + s;  Tm1b[c] = s + r;
        } else { Dm1a[c] = 0.f; Dm1b[c] = 0.f; Tm1a[c] = 0.f; Tm1b[c] = 0.f; }
        {
            float l, a, bb, r; load_row4(pl[c], r0, x0, l, a, bb, r);
            float s = a + bb;
            D0a[c] = bb - l; D0b[c] = r - a;
            T0a[c] = l + s;  T0b[c] = s + r;
        }
    }

    // Issue loads for row r0+1 (consumed at top of first iteration).
#pragma unroll
    for (int c = 0; c < 6; ++c)
        load_row4(pl[c], r0 + 1, x0, Rl[c], Ra[c], Rb[c], Rr[c]);  // r0+1 <= 369 < HH
    float2 mrow = *reinterpret_cast<const float2*>(mpl + (size_t)r0 * WW + x0);

    float lsum = 0.f, msum = 0.f;

#pragma unroll 2    // rolling loop: keeps VGPR below the 128 tier, rename-by-2
    for (int k = 0; k < ROWS; ++k) {
        const int i = r0 + k;

        // Consume lookahead -> D/T for row i+1 (loads issued one iter ago).
        float Dp1a[6], Dp1b[6], Tp1a[6], Tp1b[6];
#pragma unroll
        for (int c = 0; c < 6; ++c) {
            float s = Ra[c] + Rb[c];
            Dp1a[c] = Rb[c] - Rl[c]; Dp1b[c] = Rr[c] - Ra[c];
            Tp1a[c] = Rl[c] + s;     Tp1b[c] = s + Rr[c];
        }
        const float2 m = mrow;

        // Prefetch row i+2 (+ next mask row) NOW, overlapping the math below.
        if (i + 2 < HH) {   // uniform per block
#pragma unroll
            for (int c = 0; c < 6; ++c) load_row4(pl[c], i + 2, x0, Rl[c], Ra[c], Rb[c], Rr[c]);
        } else {
#pragma unroll
            for (int c = 0; c < 6; ++c) { Rl[c] = 0.f; Ra[c] = 0.f; Rb[c] = 0.f; Rr[c] = 0.f; }
        }
        if (k + 1 < ROWS) mrow = *reinterpret_cast<const float2*>(mpl + (size_t)(i + 1) * WW + x0);

        // Gradients (global factor 3 dropped; cancels in normalization)
        float gxa[6], gxb[6], gya[6], gyb[6];
#pragma unroll
        for (int c = 0; c < 6; ++c) {
            gxa[c] = Dm1a[c] + D0a[c] + Dp1a[c];
            gxb[c] = Dm1b[c] + D0b[c] + Dp1b[c];
            gya[c] = Tp1a[c] - Tm1a[c];
            gyb[c] = Tp1b[c] - Tm1b[c];
        }

        const float da = normal_absdiff(gxa[0], gxa[1], gxa[2], gxa[3], gxa[4], gxa[5],
                                        gya[0], gya[1], gya[2], gya[3], gya[4], gya[5]);
        const float db = normal_absdiff(gxb[0], gxb[1], gxb[2], gxb[3], gxb[4], gxb[5],
                                        gyb[0], gyb[1], gyb[2], gyb[3], gyb[4], gyb[5]);

        lsum += m.x * da + m.y * db;
        msum += m.x + m.y;

        // Rotate rolling state (plain copies; unroll-2 lets compiler rename).
#pragma unroll
        for (int c = 0; c < 6; ++c) {
            Dm1a[c] = D0a[c]; D0a[c] = Dp1a[c];
            Dm1b[c] = D0b[c]; D0b[c] = Dp1b[c];
            Tm1a[c] = T0a[c]; T0a[c] = Tp1a[c];
            Tm1b[c] = T0b[c]; T0b[c] = Tp1b[c];
        }
    }

    // Wave(64) shuffle reduction, cross-wave via LDS, one atomic pair per block.
#pragma unroll
    for (int off = 32; off > 0; off >>= 1) {
        lsum += __shfl_down(lsum, off, 64);
        msum += __shfl_down(msum, off, 64);
    }
    __shared__ float sL[TPB / 64], sM[TPB / 64];
    const int lane = threadIdx.x & 63;
    const int wid  = threadIdx.x >> 6;
    if (lane == 0) { sL[wid] = lsum; sM[wid] = msum; }
    __syncthreads();
    if (threadIdx.x == 0) {
        float L = 0.f, M = 0.f;
#pragma unroll
        for (int w = 0; w < TPB / 64; ++w) { L += sL[w]; M += sM[w]; }
        const int linear = (blockIdx.z * gridDim.y + blockIdx.y) * gridDim.x + blockIdx.x;
        double* slot = acc + (size_t)(linear & (NSLOT - 1)) * 8;  // 64B stride
        atomicAdd(&slot[0], (double)L);
        atomicAdd(&slot[1], (double)M);
    }
}

__global__ void NormalLoss_44478681317469_final(const double* __restrict__ acc,
                                                float* __restrict__ out)
{
    const int t = threadIdx.x;   // 64 threads, one per slot
    double L = acc[(size_t)t * 8 + 0];
    double M = acc[(size_t)t * 8 + 1];
#pragma unroll
    for (int off = 32; off > 0; off >>= 1) {
        L += __shfl_down(L, off, 64);
        M += __shfl_down(M, off, 64);
    }
    if (t == 0) out[0] = (float)(L / M);
}

extern "C" void kernel_launch(void* const* d_in, const int* in_sizes, int n_in,
                              void* d_out, int out_size, void* d_ws, size_t ws_size,
                              hipStream_t stream)
{
    const float* pred = (const float*)d_in[0];
    const float* gt   = (const float*)d_in[1];
    const float* mask = (const float*)d_in[2];
    double* acc = (double*)d_ws;

    // d_ws is poisoned 0xAA before every timed launch — zero the slot array.
    hipMemsetAsync(acc, 0, NSLOT * 8 * sizeof(double), stream);

    dim3 grid(WW / (TPB * VEC), HH / ROWS, BB);   // 5 x 24 x 16 = 1920 blocks
    NormalLoss_44478681317469_main<<<grid, dim3(TPB), 0, stream>>>(pred, gt, mask, acc);
    NormalLoss_44478681317469_final<<<1, 64, 0, stream>>>(acc, (float*)d_out);
}

// Round 3
// 242.737 us; speedup vs baseline: 1.0548x; 1.0548x over previous
//
#include <hip/hip_runtime.h>

// Problem constants (B,C,H,W fixed by setup_inputs)
#define BB  16
#define HH  384
#define WW  1280
#define ROWS 16       // rows per strip: 24 strips
#define CPW 62        // output columns per wave (lanes 0,63 = halo)
#define NGROUP 21     // ceil(1280/62); 21*62 = 1302 covers WW with 98% lane util
#define NSLOT 64      // accumulator slots, one 64B line each

// R3 theory: R1/R2 showed per-wave load-batch latency (~3k cy) * resident
// waves is the wall, and 2/3 of the 19 loads/iter were horizontal re-reads
// (taps j-1,j,j+1 each fetched by 3 threads). This version loads each element
// ONCE (7 VMEM/iter) and gets taps via wave shuffles. Single-wave blocks:
// no barriers, no LDS staging, 8064 independent waves.

__device__ __forceinline__ float load_col(const float* __restrict__ plane,
                                          int i, int j, bool jok) {
    return jok ? plane[(size_t)i * WW + j] : 0.f;   // zero col-padding
}

// horizontal taps from raw per-lane value v (lane l holds column j = base+l-1):
// l-tap = lane-1's v, r-tap = lane+1's v. Edge lanes get garbage -> unused.
__device__ __forceinline__ void taps(float v, float& D, float& T) {
    const float lft = __shfl_up(v, 1, 64);
    const float rgt = __shfl_down(v, 1, 64);
    D = rgt - lft;
    T = lft + v + rgt;
}

// Per-column finish: cross products, normalize (rsq), |pred-gt| sum over xyz.
__device__ __forceinline__ float normal_absdiff(const float* gx, const float* gy)
{
    float n0p = gx[1] * gy[2] - gx[2] * gy[1];
    float n1p = gx[2] * gy[0] - gx[0] * gy[2];
    float n2p = gx[0] * gy[1] - gx[1] * gy[0];
    float n0g = gx[4] * gy[5] - gx[5] * gy[4];
    float n1g = gx[5] * gy[3] - gx[3] * gy[5];
    float n2g = gx[3] * gy[4] - gx[4] * gy[3];
    float sp = n0p * n0p + n1p * n1p + n2p * n2p;
    float sg = n0g * n0g + n1g * n1g + n2g * n2g;
    // ref: normal/(sqrt(s)+1e-10); rsq rel-err ~2e-6; guard s~0 -> 0
    float ip = (sp > 1e-20f) ? __builtin_amdgcn_rsqf(sp) : 0.f;
    float ig = (sg > 1e-20f) ? __builtin_amdgcn_rsqf(sg) : 0.f;
    return fabsf(n0p * ip - n0g * ig) + fabsf(n1p * ip - n1g * ig)
         + fabsf(n2p * ip - n2g * ig);
}

__global__ __launch_bounds__(64)
void NormalLoss_44478681317469_main(const float* __restrict__ pred,
                                    const float* __restrict__ gt,
                                    const float* __restrict__ mask,
                                    double* __restrict__ acc)
{
    const int lane = threadIdx.x;                     // 0..63
    const int j    = blockIdx.x * CPW - 1 + lane;     // my column (lane0: halo-left)
    const bool jok = (unsigned)j < WW;                // col in range (handles j=-1)
    const int r0   = blockIdx.y * ROWS;               // strip start row
    const int b    = blockIdx.z;
    // lanes 1..62 with valid column produce output
    const bool out_ok = (lane >= 1) && (lane <= CPW) && jok;

    const float* pl[6];
#pragma unroll
    for (int c = 0; c < 3; ++c) {
        pl[c]     = pred + (size_t)(b * 3 + c) * HH * WW;
        pl[3 + c] = gt   + (size_t)(b * 3 + c) * HH * WW;
    }
    const float* mpl = mask + (size_t)b * HH * WW;

    // Rolling D (horiz diff) / T (horiz sum) state for rows i-1, i.
    float Dm1[6], D0[6], Tm1[6], T0[6];
    // Raw lookahead: row i+1 currently in flight (6 regs, was 18 in R1).
    float Rv[6];

#pragma unroll
    for (int c = 0; c < 6; ++c) {
        if (r0 > 0) {   // uniform per block
            float v = load_col(pl[c], r0 - 1, j, jok);
            taps(v, Dm1[c], Tm1[c]);
        } else { Dm1[c] = 0.f; Tm1[c] = 0.f; }   // zero padding above row 0
        {
            float v = load_col(pl[c], r0, j, jok);
            taps(v, D0[c], T0[c]);
        }
    }

    // Issue loads for row r0+1 (consumed at top of first iteration).
#pragma unroll
    for (int c = 0; c < 6; ++c)
        Rv[c] = load_col(pl[c], r0 + 1, j, jok);      // r0+1 <= 369 < HH
    float mrow = jok ? mpl[(size_t)r0 * WW + j] : 0.f;

    float lsum = 0.f, msum = 0.f;

#pragma unroll 2    // rolling loop: rename-by-2 for the rotate copies
    for (int k = 0; k < ROWS; ++k) {
        const int i = r0 + k;

        // Consume lookahead -> D/T for row i+1 via shuffles.
        float Dp1[6], Tp1[6];
#pragma unroll
        for (int c = 0; c < 6; ++c) taps(Rv[c], Dp1[c], Tp1[c]);
        const float m = out_ok ? mrow : 0.f;   // folds lane/col masking into sums

        // Prefetch row i+2 (+ next mask row) NOW, overlapping the math below.
        if (i + 2 < HH) {   // uniform per block
#pragma unroll
            for (int c = 0; c < 6; ++c) Rv[c] = load_col(pl[c], i + 2, j, jok);
        } else {
#pragma unroll
            for (int c = 0; c < 6; ++c) Rv[c] = 0.f;
        }
        if (k + 1 < ROWS) mrow = jok ? mpl[(size_t)(i + 1) * WW + j] : 0.f;

        // Gradients (global factor 3 dropped; cancels in normalization)
        float gx[6], gy[6];
#pragma unroll
        for (int c = 0; c < 6; ++c) {
            gx[c] = Dm1[c] + D0[c] + Dp1[c];
            gy[c] = Tp1[c] - Tm1[c];
        }

        const float d = normal_absdiff(gx, gy);
        lsum += m * d;
        msum += m;

        // Rotate rolling state (plain copies; unroll-2 lets compiler rename).
#pragma unroll
        for (int c = 0; c < 6; ++c) {
            Dm1[c] = D0[c]; D0[c] = Dp1[c];
            Tm1[c] = T0[c]; T0[c] = Tp1[c];
        }
    }

    // Single-wave block: pure shuffle reduction, one atomic pair per block.
#pragma unroll
    for (int off = 32; off > 0; off >>= 1) {
        lsum += __shfl_down(lsum, off, 64);
        msum += __shfl_down(msum, off, 64);
    }
    if (lane == 0) {
        const int linear = (blockIdx.z * gridDim.y + blockIdx.y) * gridDim.x + blockIdx.x;
        double* slot = acc + (size_t)(linear & (NSLOT - 1)) * 8;  // 64B stride
        atomicAdd(&slot[0], (double)lsum);
        atomicAdd(&slot[1], (double)msum);
    }
}

__global__ void NormalLoss_44478681317469_final(const double* __restrict__ acc,
                                                float* __restrict__ out)
{
    const int t = threadIdx.x;   // 64 threads, one per slot
    double L = acc[(size_t)t * 8 + 0];
    double M = acc[(size_t)t * 8 + 1];
#pragma unroll
    for (int off = 32; off > 0; off >>= 1) {
        L += __shfl_down(L, off, 64);
        M += __shfl_down(M, off, 64);
    }
    if (t == 0) out[0] = (float)(L / M);
}

extern "C" void kernel_launch(void* const* d_in, const int* in_sizes, int n_in,
                              void* d_out, int out_size, void* d_ws, size_t ws_size,
                              hipStream_t stream)
{
    const float* pred = (const float*)d_in[0];
    const float* gt   = (const float*)d_in[1];
    const float* mask = (const float*)d_in[2];
    double* acc = (double*)d_ws;

    // d_ws is poisoned 0xAA before every timed launch — zero the slot array.
    hipMemsetAsync(acc, 0, NSLOT * 8 * sizeof(double), stream);

    dim3 grid(NGROUP, HH / ROWS, BB);   // 21 x 24 x 16 = 8064 single-wave blocks
    NormalLoss_44478681317469_main<<<grid, dim3(64), 0, stream>>>(pred, gt, mask, acc);
    NormalLoss_44478681317469_final<<<1, 64, 0, stream>>>(acc, (float*)d_out);
}